// Round 2
// baseline (575.112 us; speedup 1.0000x reference)
//
#include <hip/hip_runtime.h>

typedef __attribute__((ext_vector_type(4))) float f32x4;
typedef __attribute__((ext_vector_type(8))) short s16x8;

#define MFMA16(a,b,c) __builtin_amdgcn_mfma_f32_16x16x32_bf16(a,b,c,0,0,0)

__device__ __forceinline__ unsigned short f2bf(float f){
  unsigned u = __float_as_uint(f);
  u += 0x7FFFu + ((u >> 16) & 1u);
  return (unsigned short)(u >> 16);
}

// ---------------- prep: transpose weights to bf16 N-major, fold q scale ----
__global__ void k_prep(const float* __restrict__ qkv_w,   // (512,1536)
                       const float* __restrict__ qkv_b,   // (1536)
                       const float* __restrict__ proj_w,  // (512,512)
                       unsigned short* __restrict__ wqkv_t,  // (1536,512) bf16
                       unsigned short* __restrict__ wproj_t, // (512,512) bf16
                       float* __restrict__ bqkv_s)           // (1536) f32
{
  const float scale = 0.17677669529663687f; // 32^-0.5
  int tid = blockIdx.x * blockDim.x + threadIdx.x;
  int np  = gridDim.x * blockDim.x;
  for (int i = tid; i < 1536*512; i += np){
    int c = i >> 9, k = i & 511;
    float w = qkv_w[k*1536 + c];
    if (c < 512) w *= scale;
    wqkv_t[i] = f2bf(w);
  }
  for (int i = tid; i < 512*512; i += np){
    int c = i >> 9, k = i & 511;
    wproj_t[i] = f2bf(proj_w[k*512 + c]);
  }
  for (int i = tid; i < 1536; i += np){
    float bv = qkv_b[i];
    if (i < 512) bv *= scale;
    bqkv_s[i] = bv;
  }
}

// ---------------- fused qkv GEMM + window attention ------------------------
// grid: 1024 windows * 4 head-groups; block 256 = 4 waves; wave <-> one head.
// Per-wave LDS (ushorts): q [64][40] (2560) | k [64][40] (2560) | vT [32][72] (2304)
// P [64][72] (4608) overlays q+k after they are consumed. Total 7424/wave.
__global__ __launch_bounds__(256, 2) void k_qkv_attn(
    const float* __restrict__ x,              // (1024,49,512) f32
    const unsigned short* __restrict__ wqkv_t,// (1536,512) bf16 (q cols pre-scaled)
    const float* __restrict__ bqkv_s,         // (1536) f32 (q part pre-scaled)
    const float* __restrict__ btab,           // (169,16) f32
    unsigned short* __restrict__ att)         // (1024,49,512) bf16
{
  __shared__ unsigned short lds[4*7424];
  const int lane = threadIdx.x & 63;
  const int wave = threadIdx.x >> 6;
  const int b    = blockIdx.x >> 2;
  const int h    = ((blockIdx.x & 3) << 2) | wave;
  const int l16  = lane & 15;
  const int lg   = lane >> 4;   // 0..3
  const f32x4 ZERO4 = {0.f, 0.f, 0.f, 0.f};

  unsigned short* q_lds = lds + wave*7424;   // [64][40]
  unsigned short* k_lds = q_lds + 2560;      // [64][40]
  unsigned short* vT    = q_lds + 5120;      // [32][72]
  unsigned short* p_lds = q_lds;             // [64][72] overlay

  // ---- qkv GEMM: out rows 0..63 (tokens, >=49 zero-padded), 3x32 cols ----
  f32x4 acc[3][4][2];
  #pragma unroll
  for (int a=0;a<3;++a)
    #pragma unroll
    for (int rt=0;rt<4;++rt)
      #pragma unroll
      for (int ct=0;ct<2;++ct)
        acc[a][rt][ct] = ZERO4;

  const float* xb = x + (size_t)b * 49 * 512;
  const int cbase = h * 32;

  #pragma unroll 2
  for (int ks = 0; ks < 16; ++ks){
    const int k0 = ks*32 + lg*8;
    s16x8 afrag[4];
    #pragma unroll
    for (int rt=0; rt<4; ++rt){
      const int n = rt*16 + l16;
      f32x4 v0 = ZERO4, v1 = ZERO4;
      if (n < 49){
        const float* p = xb + n*512 + k0;
        v0 = *(const f32x4*)p;
        v1 = *(const f32x4*)(p + 4);
      }
      s16x8 t;
      t[0]=(short)f2bf(v0[0]); t[1]=(short)f2bf(v0[1]);
      t[2]=(short)f2bf(v0[2]); t[3]=(short)f2bf(v0[3]);
      t[4]=(short)f2bf(v1[0]); t[5]=(short)f2bf(v1[1]);
      t[6]=(short)f2bf(v1[2]); t[7]=(short)f2bf(v1[3]);
      afrag[rt] = t;
    }
    s16x8 bfrag[3][2];
    #pragma unroll
    for (int wq=0;wq<3;++wq)
      #pragma unroll
      for (int ct=0;ct<2;++ct){
        const int c = wq*512 + cbase + ct*16 + l16;
        bfrag[wq][ct] = *(const s16x8*)(wqkv_t + (size_t)c*512 + k0);
      }
    #pragma unroll
    for (int wq=0;wq<3;++wq)
      #pragma unroll
      for (int rt=0;rt<4;++rt)
        #pragma unroll
        for (int ct=0;ct<2;++ct)
          acc[wq][rt][ct] = MFMA16(afrag[rt], bfrag[wq][ct], acc[wq][rt][ct]);
  }

  // ---- epilogue: +bias, cvt bf16, stash q/k (row-major) and v (transposed)
  #pragma unroll
  for (int wq=0; wq<3; ++wq){
    #pragma unroll
    for (int ct=0; ct<2; ++ct){
      const int c = wq*512 + cbase + ct*16 + l16;
      const float bv = bqkv_s[c];
      #pragma unroll
      for (int rt=0; rt<4; ++rt){
        f32x4 vv = acc[wq][rt][ct];
        const int row0 = rt*16 + lg*4;
        if (wq == 0){
          #pragma unroll
          for (int r=0;r<4;++r) q_lds[(row0+r)*40 + ct*16 + l16] = f2bf(vv[r]+bv);
        } else if (wq == 1){
          #pragma unroll
          for (int r=0;r<4;++r) k_lds[(row0+r)*40 + ct*16 + l16] = f2bf(vv[r]+bv);
        } else {
          ushort4 pk;
          pk.x=f2bf(vv[0]+bv); pk.y=f2bf(vv[1]+bv);
          pk.z=f2bf(vv[2]+bv); pk.w=f2bf(vv[3]+bv);
          *(ushort4*)&vT[(ct*16+l16)*72 + row0] = pk;  // vT[dd][n0..n0+3]
        }
      }
    }
  }

  // ---- scores S = q @ k^T  (64x64, K=32 -> 1 MFMA per tile) ----
  s16x8 aq[4], bk[4];
  #pragma unroll
  for (int t=0;t<4;++t){
    aq[t] = *(const s16x8*)&q_lds[(t*16+l16)*40 + lg*8];
    bk[t] = *(const s16x8*)&k_lds[(t*16+l16)*40 + lg*8];
  }
  f32x4 sacc[4][4];
  #pragma unroll
  for (int rt=0;rt<4;++rt)
    #pragma unroll
    for (int ct=0;ct<4;++ct)
      sacc[rt][ct] = MFMA16(aq[rt], bk[ct], ZERO4);

  // ---- bias + mask + row softmax; P -> LDS (overlays q/k) ----
  int colv[4], kyv[4], kxv[4];
  #pragma unroll
  for (int ct=0;ct<4;++ct){
    colv[ct] = ct*16 + l16;
    kyv[ct]  = colv[ct] / 7;
    kxv[ct]  = colv[ct] % 7;
  }
  #pragma unroll
  for (int rt=0;rt<4;++rt){
    #pragma unroll
    for (int r=0;r<4;++r){
      const int row = rt*16 + lg*4 + r;
      const int qy = row / 7, qx = row % 7;
      float sv[4];
      #pragma unroll
      for (int ct=0;ct<4;++ct){
        float s = sacc[rt][ct][r];
        if (row < 49 && colv[ct] < 49){
          const int idx = (qy - kyv[ct] + 6)*13 + (qx - kxv[ct] + 6);
          s += btab[idx*16 + h];
        }
        if (colv[ct] >= 49) s = -1e30f;
        else if (row >= 49) s = 0.f;
        sv[ct] = s;
      }
      float m = fmaxf(fmaxf(sv[0],sv[1]), fmaxf(sv[2],sv[3]));
      #pragma unroll
      for (int d=1; d<16; d<<=1) m = fmaxf(m, __shfl_xor(m, d));
      float e0 = __expf(sv[0]-m), e1 = __expf(sv[1]-m);
      float e2 = __expf(sv[2]-m), e3 = __expf(sv[3]-m);
      float sum = e0+e1+e2+e3;
      #pragma unroll
      for (int d=1; d<16; d<<=1) sum += __shfl_xor(sum, d);
      const float inv = 1.f / sum;
      p_lds[row*72 + colv[0]] = f2bf(e0*inv);
      p_lds[row*72 + colv[1]] = f2bf(e1*inv);
      p_lds[row*72 + colv[2]] = f2bf(e2*inv);
      p_lds[row*72 + colv[3]] = f2bf(e3*inv);
    }
  }

  // ---- O = P @ v  (64x64 @ 64x32) ----
  f32x4 oacc[4][2];
  #pragma unroll
  for (int rt=0;rt<4;++rt)
    #pragma unroll
    for (int ct=0;ct<2;++ct)
      oacc[rt][ct] = ZERO4;
  #pragma unroll
  for (int kt=0; kt<2; ++kt){
    s16x8 ap[4], bv2[2];
    #pragma unroll
    for (int rt=0;rt<4;++rt)
      ap[rt] = *(const s16x8*)&p_lds[(rt*16+l16)*72 + kt*32 + lg*8];
    #pragma unroll
    for (int ct=0;ct<2;++ct)
      bv2[ct] = *(const s16x8*)&vT[(ct*16+l16)*72 + kt*32 + lg*8];
    #pragma unroll
    for (int rt=0;rt<4;++rt)
      #pragma unroll
      for (int ct=0;ct<2;++ct)
        oacc[rt][ct] = MFMA16(ap[rt], bv2[ct], oacc[rt][ct]);
  }

  // ---- restage O through LDS (reuse P region) for coalesced bf16 stores ----
  unsigned short* o_lds = p_lds;  // [64][40]
  #pragma unroll
  for (int rt=0;rt<4;++rt)
    #pragma unroll
    for (int ct=0;ct<2;++ct){
      const int row0 = rt*16 + lg*4;
      f32x4 vv = oacc[rt][ct];
      #pragma unroll
      for (int r=0;r<4;++r)
        o_lds[(row0+r)*40 + ct*16 + l16] = f2bf(vv[r]);
    }
  unsigned short* attb = att + (size_t)b*49*512 + h*32;
  for (int i = lane; i < 49*4; i += 64){
    const int row = i >> 2, seg = i & 3;
    *(s16x8*)&attb[(size_t)row*512 + seg*8] = *(const s16x8*)&o_lds[row*40 + seg*8];
  }
}

// ---------------- proj GEMM: out = att(bf16) @ proj_w + b, fp32 out --------
// LDS-free: fragments straight from L1/L2. Wave = 64x64 tile; block = 128x128.
__global__ __launch_bounds__(256) void k_proj(
    const unsigned short* __restrict__ att,    // (50176,512) bf16
    const unsigned short* __restrict__ wproj_t,// (512,512) bf16, [c][k]
    const float* __restrict__ proj_b,          // (512)
    float* __restrict__ out)                   // (50176,512) f32
{
  const int lane = threadIdx.x & 63;
  const int wave = threadIdx.x >> 6;
  const int l16  = lane & 15;
  const int lg   = lane >> 4;
  const int mb = blockIdx.x >> 2;   // 0..391
  const int nb = blockIdx.x & 3;    // 0..3
  const int m0 = mb*128 + (wave>>1)*64;
  const int n0 = nb*128 + (wave&1)*64;
  const f32x4 ZERO4 = {0.f, 0.f, 0.f, 0.f};

  f32x4 acc[4][4];
  #pragma unroll
  for (int rt=0;rt<4;++rt)
    #pragma unroll
    for (int ct=0;ct<4;++ct)
      acc[rt][ct] = ZERO4;

  #pragma unroll 2
  for (int ks=0; ks<16; ++ks){
    const int k0 = ks*32 + lg*8;
    s16x8 a[4], bw[4];
    #pragma unroll
    for (int t=0;t<4;++t){
      a[t]  = *(const s16x8*)(att     + (size_t)(m0 + t*16 + l16)*512 + k0);
      bw[t] = *(const s16x8*)(wproj_t + (size_t)(n0 + t*16 + l16)*512 + k0);
    }
    #pragma unroll
    for (int rt=0;rt<4;++rt)
      #pragma unroll
      for (int ct=0;ct<4;++ct)
        acc[rt][ct] = MFMA16(a[rt], bw[ct], acc[rt][ct]);
  }

  #pragma unroll
  for (int ct=0;ct<4;++ct){
    const float bv = proj_b[n0 + ct*16 + l16];
    #pragma unroll
    for (int rt=0;rt<4;++rt){
      const int row = m0 + rt*16 + lg*4;
      #pragma unroll
      for (int r=0;r<4;++r)
        out[(size_t)(row+r)*512 + n0 + ct*16 + l16] = acc[rt][ct][r] + bv;
    }
  }
}

// ---------------- launcher -------------------------------------------------
extern "C" void kernel_launch(void* const* d_in, const int* in_sizes, int n_in,
                              void* d_out, int out_size, void* d_ws, size_t ws_size,
                              hipStream_t stream)
{
  const float* x      = (const float*)d_in[0];
  const float* qkv_w  = (const float*)d_in[1];
  const float* qkv_b  = (const float*)d_in[2];
  const float* btab   = (const float*)d_in[3];
  const float* proj_w = (const float*)d_in[4];
  const float* proj_b = (const float*)d_in[5];
  float* out = (float*)d_out;

  char* ws = (char*)d_ws;
  unsigned short* att     = (unsigned short*)ws;                    // 51,380,224 B
  unsigned short* wqkv_t  = (unsigned short*)(ws + 51380224);       // 1,572,864 B
  unsigned short* wproj_t = (unsigned short*)(ws + 51380224 + 1572864); // 524,288 B
  float*          bqkv_s  = (float*)(ws + 51380224 + 1572864 + 524288); // 6,144 B

  k_prep<<<512, 256, 0, stream>>>(qkv_w, qkv_b, proj_w, wqkv_t, wproj_t, bqkv_s);
  k_qkv_attn<<<1024*4, 256, 0, stream>>>(x, wqkv_t, bqkv_s, btab, att);
  k_proj<<<392*4, 256, 0, stream>>>(att, wproj_t, proj_b, out);
}

// Round 3
// 443.155 us; speedup vs baseline: 1.2978x; 1.2978x over previous
//
#include <hip/hip_runtime.h>

typedef __attribute__((ext_vector_type(4))) float f32x4;
typedef __attribute__((ext_vector_type(8))) short s16x8;

#define MFMA16(a,b,c) __builtin_amdgcn_mfma_f32_16x16x32_bf16(a,b,c,0,0,0)

__device__ __forceinline__ unsigned short f2bf(float f){
  unsigned u = __float_as_uint(f);
  u += 0x7FFFu + ((u >> 16) & 1u);
  return (unsigned short)(u >> 16);
}

__device__ __forceinline__ void gload_lds16(const unsigned short* g, unsigned short* l){
  __builtin_amdgcn_global_load_lds(
      (const __attribute__((address_space(1))) unsigned int*)(const void*)g,
      (__attribute__((address_space(3))) unsigned int*)(void*)l,
      16, 0, 0);
}

// ---------------- x -> bf16 cast ------------------------------------------
__global__ void k_xcast(const float* __restrict__ x, unsigned short* __restrict__ xb){
  const int i = blockIdx.x * blockDim.x + threadIdx.x;   // one 8-elem chunk
  const int total = 1024*49*512/8;
  if (i < total){
    const float* p = x + (size_t)i*8;
    f32x4 v0 = *(const f32x4*)p, v1 = *(const f32x4*)(p+4);
    s16x8 t;
    t[0]=(short)f2bf(v0[0]); t[1]=(short)f2bf(v0[1]);
    t[2]=(short)f2bf(v0[2]); t[3]=(short)f2bf(v0[3]);
    t[4]=(short)f2bf(v1[0]); t[5]=(short)f2bf(v1[1]);
    t[6]=(short)f2bf(v1[2]); t[7]=(short)f2bf(v1[3]);
    *(s16x8*)(xb + (size_t)i*8) = t;
  }
}

// ---------------- prep: transpose weights to bf16 N-major, fold q scale ----
__global__ void k_prep(const float* __restrict__ qkv_w,   // (512,1536)
                       const float* __restrict__ qkv_b,   // (1536)
                       const float* __restrict__ proj_w,  // (512,512)
                       unsigned short* __restrict__ wqkv_t,  // (1536,512) bf16
                       unsigned short* __restrict__ wproj_t, // (512,512) bf16
                       float* __restrict__ bqkv_s)           // (1536) f32
{
  const float scale = 0.17677669529663687f; // 32^-0.5
  int tid = blockIdx.x * blockDim.x + threadIdx.x;
  int np  = gridDim.x * blockDim.x;
  for (int i = tid; i < 1536*512; i += np){
    int c = i >> 9, k = i & 511;
    float w = qkv_w[k*1536 + c];
    if (c < 512) w *= scale;
    wqkv_t[i] = f2bf(w);
  }
  for (int i = tid; i < 512*512; i += np){
    int c = i >> 9, k = i & 511;
    wproj_t[i] = f2bf(proj_w[k*512 + c]);
  }
  for (int i = tid; i < 1536; i += np){
    float bv = qkv_b[i];
    if (i < 512) bv *= scale;
    bqkv_s[i] = bv;
  }
}

// ---------------- fused qkv GEMM + window attention (bf16 x, LDS-staged) ---
// grid: 1024 windows * 4 head-groups; block 256 = 4 waves; wave <-> one head.
// LDS shorts: per-wave q[64][40] k[64][40] vT[32][72] (P overlays q+k) = 7424
//             + shared x-tile dbuf [2][64][32] = 4096.  Total 33792 (67.6 KB).
__global__ __launch_bounds__(256, 2) void k_qkv_attn2(
    const unsigned short* __restrict__ xb,    // (1024*49,512) bf16
    const unsigned short* __restrict__ wqkv_t,// (1536,512) bf16 (q pre-scaled)
    const float* __restrict__ bqkv_s,         // (1536) f32 (q pre-scaled)
    const float* __restrict__ btab,           // (169,16) f32
    unsigned short* __restrict__ att)         // (1024,49,512) bf16
{
  __shared__ unsigned short lds[4*7424 + 2*2048];
  const int lane = threadIdx.x & 63;
  const int wave = threadIdx.x >> 6;
  const int b    = blockIdx.x >> 2;
  const int h    = ((blockIdx.x & 3) << 2) | wave;
  const int l16  = lane & 15;
  const int lg   = lane >> 4;   // 0..3
  const f32x4 ZERO4 = {0.f, 0.f, 0.f, 0.f};

  unsigned short* q_lds  = lds + wave*7424;   // [64][40]
  unsigned short* k_lds  = q_lds + 2560;      // [64][40]
  unsigned short* vT     = q_lds + 5120;      // [32][72]
  unsigned short* p_lds  = q_lds;             // [64][72] overlay
  unsigned short* xstage = lds + 4*7424;      // [2][64][32]

  // zero-seed rows 49..63 of both x buffers (never re-written)
  for (int i = threadIdx.x; i < 2*15*32; i += 256){
    int bf = i / 480, rem = i % 480;
    xstage[bf*2048 + (49 + rem/32)*32 + (rem & 31)] = 0;
  }

  const unsigned short* xwin = xb + (size_t)b*49*512;
  const int srow = wave*16 + (lane>>2);      // row this lane stages
  const int scol = (lane&3)*8;               // col offset (8 bf16 = 16B)

  __syncthreads();  // zero-seed visible
  // prologue: stage kstep 0 into buf 0
  if (srow < 49)
    gload_lds16(xwin + (size_t)srow*512 + scol, xstage + wave*512);
  __syncthreads();  // drains vmcnt -> tile 0 resident

  // ---- qkv GEMM: 64 tokens x (3 x 32) cols for head h ----
  f32x4 acc[3][4][2];
  #pragma unroll
  for (int a=0;a<3;++a)
    #pragma unroll
    for (int rt=0;rt<4;++rt)
      #pragma unroll
      for (int ct=0;ct<2;++ct)
        acc[a][rt][ct] = ZERO4;

  const int cbase = h * 32;

  #pragma unroll 2
  for (int ks = 0; ks < 16; ++ks){
    const int p = ks & 1;
    if (ks < 15 && srow < 49)
      gload_lds16(xwin + (size_t)srow*512 + (ks+1)*32 + scol,
                  xstage + ((ks+1)&1)*2048 + wave*512);

    s16x8 afrag[4];
    #pragma unroll
    for (int rt=0; rt<4; ++rt)
      afrag[rt] = *(const s16x8*)&xstage[p*2048 + (rt*16 + l16)*32 + lg*8];

    s16x8 bfrag[3][2];
    #pragma unroll
    for (int wq=0;wq<3;++wq)
      #pragma unroll
      for (int ct=0;ct<2;++ct){
        const int c = wq*512 + cbase + ct*16 + l16;
        bfrag[wq][ct] = *(const s16x8*)(wqkv_t + (size_t)c*512 + ks*32 + lg*8);
      }
    #pragma unroll
    for (int wq=0;wq<3;++wq)
      #pragma unroll
      for (int rt=0;rt<4;++rt)
        #pragma unroll
        for (int ct=0;ct<2;++ct)
          acc[wq][rt][ct] = MFMA16(afrag[rt], bfrag[wq][ct], acc[wq][rt][ct]);

    __syncthreads();  // all reads of buf p done; stage(ks+1) landed
  }

  // ---- epilogue: +bias, cvt bf16, stash q/k (row-major) and v (transposed)
  #pragma unroll
  for (int wq=0; wq<3; ++wq){
    #pragma unroll
    for (int ct=0; ct<2; ++ct){
      const int c = wq*512 + cbase + ct*16 + l16;
      const float bv = bqkv_s[c];
      #pragma unroll
      for (int rt=0; rt<4; ++rt){
        f32x4 vv = acc[wq][rt][ct];
        const int row0 = rt*16 + lg*4;
        if (wq == 0){
          #pragma unroll
          for (int r=0;r<4;++r) q_lds[(row0+r)*40 + ct*16 + l16] = f2bf(vv[r]+bv);
        } else if (wq == 1){
          #pragma unroll
          for (int r=0;r<4;++r) k_lds[(row0+r)*40 + ct*16 + l16] = f2bf(vv[r]+bv);
        } else {
          ushort4 pk;
          pk.x=f2bf(vv[0]+bv); pk.y=f2bf(vv[1]+bv);
          pk.z=f2bf(vv[2]+bv); pk.w=f2bf(vv[3]+bv);
          *(ushort4*)&vT[(ct*16+l16)*72 + row0] = pk;  // vT[dd][n0..n0+3]
        }
      }
    }
  }

  // ---- scores S = q @ k^T ----
  s16x8 aq[4], bk[4];
  #pragma unroll
  for (int t=0;t<4;++t){
    aq[t] = *(const s16x8*)&q_lds[(t*16+l16)*40 + lg*8];
    bk[t] = *(const s16x8*)&k_lds[(t*16+l16)*40 + lg*8];
  }
  f32x4 sacc[4][4];
  #pragma unroll
  for (int rt=0;rt<4;++rt)
    #pragma unroll
    for (int ct=0;ct<4;++ct)
      sacc[rt][ct] = MFMA16(aq[rt], bk[ct], ZERO4);

  // ---- bias + mask + row softmax; P -> LDS ----
  int colv[4], kyv[4], kxv[4];
  #pragma unroll
  for (int ct=0;ct<4;++ct){
    colv[ct] = ct*16 + l16;
    kyv[ct]  = colv[ct] / 7;
    kxv[ct]  = colv[ct] % 7;
  }
  #pragma unroll
  for (int rt=0;rt<4;++rt){
    #pragma unroll
    for (int r=0;r<4;++r){
      const int row = rt*16 + lg*4 + r;
      const int qy = row / 7, qx = row % 7;
      float sv[4];
      #pragma unroll
      for (int ct=0;ct<4;++ct){
        float s = sacc[rt][ct][r];
        if (row < 49 && colv[ct] < 49){
          const int idx = (qy - kyv[ct] + 6)*13 + (qx - kxv[ct] + 6);
          s += btab[idx*16 + h];
        }
        if (colv[ct] >= 49) s = -1e30f;
        else if (row >= 49) s = 0.f;
        sv[ct] = s;
      }
      float m = fmaxf(fmaxf(sv[0],sv[1]), fmaxf(sv[2],sv[3]));
      #pragma unroll
      for (int d=1; d<16; d<<=1) m = fmaxf(m, __shfl_xor(m, d));
      float e0 = __expf(sv[0]-m), e1 = __expf(sv[1]-m);
      float e2 = __expf(sv[2]-m), e3 = __expf(sv[3]-m);
      float sum = e0+e1+e2+e3;
      #pragma unroll
      for (int d=1; d<16; d<<=1) sum += __shfl_xor(sum, d);
      const float inv = 1.f / sum;
      p_lds[row*72 + colv[0]] = f2bf(e0*inv);
      p_lds[row*72 + colv[1]] = f2bf(e1*inv);
      p_lds[row*72 + colv[2]] = f2bf(e2*inv);
      p_lds[row*72 + colv[3]] = f2bf(e3*inv);
    }
  }

  // ---- O = P @ v ----
  f32x4 oacc[4][2];
  #pragma unroll
  for (int rt=0;rt<4;++rt)
    #pragma unroll
    for (int ct=0;ct<2;++ct)
      oacc[rt][ct] = ZERO4;
  #pragma unroll
  for (int kt=0; kt<2; ++kt){
    s16x8 ap[4], bv2[2];
    #pragma unroll
    for (int rt=0;rt<4;++rt)
      ap[rt] = *(const s16x8*)&p_lds[(rt*16+l16)*72 + kt*32 + lg*8];
    #pragma unroll
    for (int ct=0;ct<2;++ct)
      bv2[ct] = *(const s16x8*)&vT[(ct*16+l16)*72 + kt*32 + lg*8];
    #pragma unroll
    for (int rt=0;rt<4;++rt)
      #pragma unroll
      for (int ct=0;ct<2;++ct)
        oacc[rt][ct] = MFMA16(ap[rt], bv2[ct], oacc[rt][ct]);
  }

  // ---- restage O through LDS for coalesced bf16 stores ----
  unsigned short* o_lds = p_lds;  // [64][40]
  #pragma unroll
  for (int rt=0;rt<4;++rt)
    #pragma unroll
    for (int ct=0;ct<2;++ct){
      const int row0 = rt*16 + lg*4;
      f32x4 vv = oacc[rt][ct];
      #pragma unroll
      for (int r=0;r<4;++r)
        o_lds[(row0+r)*40 + ct*16 + l16] = f2bf(vv[r]);
    }
  unsigned short* attb = att + (size_t)b*49*512 + h*32;
  for (int i = lane; i < 49*4; i += 64){
    const int row = i >> 2, seg = i & 3;
    *(s16x8*)&attb[(size_t)row*512 + seg*8] = *(const s16x8*)&o_lds[row*40 + seg*8];
  }
}

// ---------------- fallback (round-2 kernel, f32 x direct) ------------------
__global__ __launch_bounds__(256, 2) void k_qkv_attn_f32(
    const float* __restrict__ x,
    const unsigned short* __restrict__ wqkv_t,
    const float* __restrict__ bqkv_s,
    const float* __restrict__ btab,
    unsigned short* __restrict__ att)
{
  __shared__ unsigned short lds[4*7424];
  const int lane = threadIdx.x & 63;
  const int wave = threadIdx.x >> 6;
  const int b    = blockIdx.x >> 2;
  const int h    = ((blockIdx.x & 3) << 2) | wave;
  const int l16  = lane & 15;
  const int lg   = lane >> 4;
  const f32x4 ZERO4 = {0.f, 0.f, 0.f, 0.f};

  unsigned short* q_lds = lds + wave*7424;
  unsigned short* k_lds = q_lds + 2560;
  unsigned short* vT    = q_lds + 5120;
  unsigned short* p_lds = q_lds;

  f32x4 acc[3][4][2];
  #pragma unroll
  for (int a=0;a<3;++a)
    #pragma unroll
    for (int rt=0;rt<4;++rt)
      #pragma unroll
      for (int ct=0;ct<2;++ct)
        acc[a][rt][ct] = ZERO4;

  const float* xbp = x + (size_t)b * 49 * 512;
  const int cbase = h * 32;

  #pragma unroll 2
  for (int ks = 0; ks < 16; ++ks){
    const int k0 = ks*32 + lg*8;
    s16x8 afrag[4];
    #pragma unroll
    for (int rt=0; rt<4; ++rt){
      const int n = rt*16 + l16;
      f32x4 v0 = ZERO4, v1 = ZERO4;
      if (n < 49){
        const float* p = xbp + n*512 + k0;
        v0 = *(const f32x4*)p;
        v1 = *(const f32x4*)(p + 4);
      }
      s16x8 t;
      t[0]=(short)f2bf(v0[0]); t[1]=(short)f2bf(v0[1]);
      t[2]=(short)f2bf(v0[2]); t[3]=(short)f2bf(v0[3]);
      t[4]=(short)f2bf(v1[0]); t[5]=(short)f2bf(v1[1]);
      t[6]=(short)f2bf(v1[2]); t[7]=(short)f2bf(v1[3]);
      afrag[rt] = t;
    }
    s16x8 bfrag[3][2];
    #pragma unroll
    for (int wq=0;wq<3;++wq)
      #pragma unroll
      for (int ct=0;ct<2;++ct){
        const int c = wq*512 + cbase + ct*16 + l16;
        bfrag[wq][ct] = *(const s16x8*)(wqkv_t + (size_t)c*512 + k0);
      }
    #pragma unroll
    for (int wq=0;wq<3;++wq)
      #pragma unroll
      for (int rt=0;rt<4;++rt)
        #pragma unroll
        for (int ct=0;ct<2;++ct)
          acc[wq][rt][ct] = MFMA16(afrag[rt], bfrag[wq][ct], acc[wq][rt][ct]);
  }

  #pragma unroll
  for (int wq=0; wq<3; ++wq){
    #pragma unroll
    for (int ct=0; ct<2; ++ct){
      const int c = wq*512 + cbase + ct*16 + l16;
      const float bv = bqkv_s[c];
      #pragma unroll
      for (int rt=0; rt<4; ++rt){
        f32x4 vv = acc[wq][rt][ct];
        const int row0 = rt*16 + lg*4;
        if (wq == 0){
          #pragma unroll
          for (int r=0;r<4;++r) q_lds[(row0+r)*40 + ct*16 + l16] = f2bf(vv[r]+bv);
        } else if (wq == 1){
          #pragma unroll
          for (int r=0;r<4;++r) k_lds[(row0+r)*40 + ct*16 + l16] = f2bf(vv[r]+bv);
        } else {
          ushort4 pk;
          pk.x=f2bf(vv[0]+bv); pk.y=f2bf(vv[1]+bv);
          pk.z=f2bf(vv[2]+bv); pk.w=f2bf(vv[3]+bv);
          *(ushort4*)&vT[(ct*16+l16)*72 + row0] = pk;
        }
      }
    }
  }

  s16x8 aq[4], bk[4];
  #pragma unroll
  for (int t=0;t<4;++t){
    aq[t] = *(const s16x8*)&q_lds[(t*16+l16)*40 + lg*8];
    bk[t] = *(const s16x8*)&k_lds[(t*16+l16)*40 + lg*8];
  }
  f32x4 sacc[4][4];
  #pragma unroll
  for (int rt=0;rt<4;++rt)
    #pragma unroll
    for (int ct=0;ct<4;++ct)
      sacc[rt][ct] = MFMA16(aq[rt], bk[ct], ZERO4);

  int colv[4], kyv[4], kxv[4];
  #pragma unroll
  for (int ct=0;ct<4;++ct){
    colv[ct] = ct*16 + l16;
    kyv[ct]  = colv[ct] / 7;
    kxv[ct]  = colv[ct] % 7;
  }
  #pragma unroll
  for (int rt=0;rt<4;++rt){
    #pragma unroll
    for (int r=0;r<4;++r){
      const int row = rt*16 + lg*4 + r;
      const int qy = row / 7, qx = row % 7;
      float sv[4];
      #pragma unroll
      for (int ct=0;ct<4;++ct){
        float s = sacc[rt][ct][r];
        if (row < 49 && colv[ct] < 49){
          const int idx = (qy - kyv[ct] + 6)*13 + (qx - kxv[ct] + 6);
          s += btab[idx*16 + h];
        }
        if (colv[ct] >= 49) s = -1e30f;
        else if (row >= 49) s = 0.f;
        sv[ct] = s;
      }
      float m = fmaxf(fmaxf(sv[0],sv[1]), fmaxf(sv[2],sv[3]));
      #pragma unroll
      for (int d=1; d<16; d<<=1) m = fmaxf(m, __shfl_xor(m, d));
      float e0 = __expf(sv[0]-m), e1 = __expf(sv[1]-m);
      float e2 = __expf(sv[2]-m), e3 = __expf(sv[3]-m);
      float sum = e0+e1+e2+e3;
      #pragma unroll
      for (int d=1; d<16; d<<=1) sum += __shfl_xor(sum, d);
      const float inv = 1.f / sum;
      p_lds[row*72 + colv[0]] = f2bf(e0*inv);
      p_lds[row*72 + colv[1]] = f2bf(e1*inv);
      p_lds[row*72 + colv[2]] = f2bf(e2*inv);
      p_lds[row*72 + colv[3]] = f2bf(e3*inv);
    }
  }

  f32x4 oacc[4][2];
  #pragma unroll
  for (int rt=0;rt<4;++rt)
    #pragma unroll
    for (int ct=0;ct<2;++ct)
      oacc[rt][ct] = ZERO4;
  #pragma unroll
  for (int kt=0; kt<2; ++kt){
    s16x8 ap[4], bv2[2];
    #pragma unroll
    for (int rt=0;rt<4;++rt)
      ap[rt] = *(const s16x8*)&p_lds[(rt*16+l16)*72 + kt*32 + lg*8];
    #pragma unroll
    for (int ct=0;ct<2;++ct)
      bv2[ct] = *(const s16x8*)&vT[(ct*16+l16)*72 + kt*32 + lg*8];
    #pragma unroll
    for (int rt=0;rt<4;++rt)
      #pragma unroll
      for (int ct=0;ct<2;++ct)
        oacc[rt][ct] = MFMA16(ap[rt], bv2[ct], oacc[rt][ct]);
  }

  unsigned short* o_lds = p_lds;
  #pragma unroll
  for (int rt=0;rt<4;++rt)
    #pragma unroll
    for (int ct=0;ct<2;++ct){
      const int row0 = rt*16 + lg*4;
      f32x4 vv = oacc[rt][ct];
      #pragma unroll
      for (int r=0;r<4;++r)
        o_lds[(row0+r)*40 + ct*16 + l16] = f2bf(vv[r]);
    }
  unsigned short* attb = att + (size_t)b*49*512 + h*32;
  for (int i = lane; i < 49*4; i += 64){
    const int row = i >> 2, seg = i & 3;
    *(s16x8*)&attb[(size_t)row*512 + seg*8] = *(const s16x8*)&o_lds[row*40 + seg*8];
  }
}

// ---------------- proj GEMM: out = att(bf16) @ proj_w + b, fp32 out --------
__global__ __launch_bounds__(256) void k_proj(
    const unsigned short* __restrict__ att,    // (50176,512) bf16
    const unsigned short* __restrict__ wproj_t,// (512,512) bf16, [c][k]
    const float* __restrict__ proj_b,          // (512)
    float* __restrict__ out)                   // (50176,512) f32
{
  const int lane = threadIdx.x & 63;
  const int wave = threadIdx.x >> 6;
  const int l16  = lane & 15;
  const int lg   = lane >> 4;
  const int mb = blockIdx.x >> 2;
  const int nb = blockIdx.x & 3;
  const int m0 = mb*128 + (wave>>1)*64;
  const int n0 = nb*128 + (wave&1)*64;
  const f32x4 ZERO4 = {0.f, 0.f, 0.f, 0.f};

  f32x4 acc[4][4];
  #pragma unroll
  for (int rt=0;rt<4;++rt)
    #pragma unroll
    for (int ct=0;ct<4;++ct)
      acc[rt][ct] = ZERO4;

  #pragma unroll 2
  for (int ks=0; ks<16; ++ks){
    const int k0 = ks*32 + lg*8;
    s16x8 a[4], bw[4];
    #pragma unroll
    for (int t=0;t<4;++t){
      a[t]  = *(const s16x8*)(att     + (size_t)(m0 + t*16 + l16)*512 + k0);
      bw[t] = *(const s16x8*)(wproj_t + (size_t)(n0 + t*16 + l16)*512 + k0);
    }
    #pragma unroll
    for (int rt=0;rt<4;++rt)
      #pragma unroll
      for (int ct=0;ct<4;++ct)
        acc[rt][ct] = MFMA16(a[rt], bw[ct], acc[rt][ct]);
  }

  #pragma unroll
  for (int ct=0;ct<4;++ct){
    const float bv = proj_b[n0 + ct*16 + l16];
    #pragma unroll
    for (int rt=0;rt<4;++rt){
      const int row = m0 + rt*16 + lg*4;
      #pragma unroll
      for (int r=0;r<4;++r)
        out[(size_t)(row+r)*512 + n0 + ct*16 + l16] = acc[rt][ct][r] + bv;
    }
  }
}

// ---------------- launcher -------------------------------------------------
extern "C" void kernel_launch(void* const* d_in, const int* in_sizes, int n_in,
                              void* d_out, int out_size, void* d_ws, size_t ws_size,
                              hipStream_t stream)
{
  const float* x      = (const float*)d_in[0];
  const float* qkv_w  = (const float*)d_in[1];
  const float* qkv_b  = (const float*)d_in[2];
  const float* btab   = (const float*)d_in[3];
  const float* proj_w = (const float*)d_in[4];
  const float* proj_b = (const float*)d_in[5];
  float* out = (float*)d_out;

  char* ws = (char*)d_ws;
  const size_t ATT = 51380224ULL;   // 50176*512*2
  const size_t XB  = 51380224ULL;
  const size_t WQ  = 1572864ULL;
  const size_t WP  = 524288ULL;
  const size_t need_big = ATT + XB + WQ + WP + 8192;

  if (ws_size >= need_big){
    unsigned short* att     = (unsigned short*)ws;
    unsigned short* xbb     = (unsigned short*)(ws + ATT);
    unsigned short* wqkv_t  = (unsigned short*)(ws + ATT + XB);
    unsigned short* wproj_t = (unsigned short*)(ws + ATT + XB + WQ);
    float*          bqkv_s  = (float*)(ws + ATT + XB + WQ + WP);

    k_xcast<<<12544, 256, 0, stream>>>(x, xbb);
    k_prep<<<512, 256, 0, stream>>>(qkv_w, qkv_b, proj_w, wqkv_t, wproj_t, bqkv_s);
    k_qkv_attn2<<<1024*4, 256, 0, stream>>>(xbb, wqkv_t, bqkv_s, btab, att);
    k_proj<<<392*4, 256, 0, stream>>>(att, wproj_t, proj_b, out);
  } else {
    unsigned short* att     = (unsigned short*)ws;
    unsigned short* wqkv_t  = (unsigned short*)(ws + ATT);
    unsigned short* wproj_t = (unsigned short*)(ws + ATT + WQ);
    float*          bqkv_s  = (float*)(ws + ATT + WQ + WP);

    k_prep<<<512, 256, 0, stream>>>(qkv_w, qkv_b, proj_w, wqkv_t, wproj_t, bqkv_s);
    k_qkv_attn_f32<<<1024*4, 256, 0, stream>>>(x, wqkv_t, bqkv_s, btab, att);
    k_proj<<<392*4, 256, 0, stream>>>(att, wproj_t, proj_b, out);
  }
}